// Round 1
// baseline (742.120 us; speedup 1.0000x reference)
//
#include <hip/hip_runtime.h>

// Problem: EncodecEuclideanCodebook
//   x:     [64, 2048, 128] fp32  -> N_ROWS = 131072 rows of DIM=128
//   embed: [1024, 128] fp32      -> BINS = 1024 codes
// Outputs (concatenated in d_out, all read back as float32):
//   quantize [131072*128] floats, then embed_ind [131072] floats (index values)
//
// argmax_e ( -(||x||^2 - 2 x.e + ||e||^2) ) == argmax_e ( 2 x.e - ||e||^2 )
// (per-row ||x||^2 is constant -> dropped; argmax invariant)

#define N_ROWS (64 * 2048)
#define DIM 128
#define BINS 1024
#define TM 64          // rows per block
#define TN 64          // bins per chunk
#define LDA 132        // 128 + 4 float pad: breaks 512B-stride bank aliasing, keeps 16B align

__global__ __launch_bounds__(256) void esq_kernel(const float* __restrict__ embed,
                                                  float* __restrict__ esq) {
    int bin = blockIdx.x * 256 + threadIdx.x;
    if (bin >= BINS) return;
    const float4* e4 = (const float4*)(embed + (size_t)bin * DIM);
    float s = 0.f;
#pragma unroll
    for (int q = 0; q < DIM / 4; ++q) {
        float4 v = e4[q];
        s += v.x * v.x + v.y * v.y + v.z * v.z + v.w * v.w;
    }
    esq[bin] = s;
}

__global__ __launch_bounds__(256, 2) void vq_kernel(const float* __restrict__ x,
                                                    const float* __restrict__ embed,
                                                    const float* __restrict__ esq,
                                                    float* __restrict__ out_q,
                                                    float* __restrict__ out_idx) {
    __shared__ float As[TM * LDA];      // x tile: 64 rows x 128 (padded)
    __shared__ float Bs[TN * LDA];      // embed chunk: 64 bins x 128 (padded)
    __shared__ float esq_s[BINS];
    __shared__ int final_idx[TM];

    const int t = threadIdx.x;
    const int row0 = blockIdx.x * TM;

    // stage e_sq (1024 floats)
#pragma unroll
    for (int i = 0; i < BINS / 256; ++i) esq_s[t + 256 * i] = esq[t + 256 * i];

    // stage A tile: 64x128 fp32 = 2048 float4, 8 per thread, coalesced
    {
        const float4* xg = (const float4*)(x + (size_t)row0 * DIM);
#pragma unroll
        for (int q = 0; q < 8; ++q) {
            int f = q * 256 + t;
            int r = f >> 5;   // 32 float4 per row
            int c = f & 31;
            float4 v = xg[f];
            *(float4*)&As[r * LDA + c * 4] = v;
        }
    }

    const int tx = t & 15;   // bin group within chunk (4 bins each)
    const int ty = t >> 4;   // row group (4 rows each)

    float best[4];
    int bidx[4];
#pragma unroll
    for (int i = 0; i < 4; ++i) { best[i] = -3.4e38f; bidx[i] = 0; }

    for (int chunk = 0; chunk < BINS / TN; ++chunk) {
        __syncthreads();  // protect As (chunk 0) / Bs reuse (chunk > 0)
        // stage B chunk: 64 bins x 128
        {
            const float4* eg = (const float4*)(embed + (size_t)chunk * TN * DIM);
#pragma unroll
            for (int q = 0; q < 8; ++q) {
                int f = q * 256 + t;
                int r = f >> 5;
                int c = f & 31;
                float4 v = eg[f];
                *(float4*)&Bs[r * LDA + c * 4] = v;
            }
        }
        __syncthreads();

        float acc[4][4];
#pragma unroll
        for (int i = 0; i < 4; ++i)
#pragma unroll
            for (int j = 0; j < 4; ++j) acc[i][j] = 0.f;

#pragma unroll 8
        for (int k = 0; k < DIM; k += 4) {
            float4 a[4], b[4];
#pragma unroll
            for (int i = 0; i < 4; ++i) a[i] = *(const float4*)&As[(4 * ty + i) * LDA + k];
#pragma unroll
            for (int j = 0; j < 4; ++j) b[j] = *(const float4*)&Bs[(4 * tx + j) * LDA + k];
#pragma unroll
            for (int i = 0; i < 4; ++i)
#pragma unroll
                for (int j = 0; j < 4; ++j) {
                    acc[i][j] = fmaf(a[i].x, b[j].x, acc[i][j]);
                    acc[i][j] = fmaf(a[i].y, b[j].y, acc[i][j]);
                    acc[i][j] = fmaf(a[i].z, b[j].z, acc[i][j]);
                    acc[i][j] = fmaf(a[i].w, b[j].w, acc[i][j]);
                }
        }

        const int binbase = chunk * TN + 4 * tx;
#pragma unroll
        for (int i = 0; i < 4; ++i)
#pragma unroll
            for (int j = 0; j < 4; ++j) {
                float sc = 2.f * acc[i][j] - esq_s[binbase + j];
                // bins scanned in increasing order within this thread:
                // strict > keeps first (lowest) index on exact ties
                if (sc > best[i]) { best[i] = sc; bidx[i] = binbase + j; }
            }
    }

    // cross-thread (tx) argmax reduce per row; reuse As/Bs as scratch
    __syncthreads();
    float* vals = As;           // [64][16]
    int* idxs = (int*)Bs;       // [64][16]
#pragma unroll
    for (int i = 0; i < 4; ++i) {
        int r = 4 * ty + i;
        vals[r * 16 + tx] = best[i];
        idxs[r * 16 + tx] = bidx[i];
    }
    __syncthreads();
    if (t < TM) {
        float bv = vals[t * 16];
        int bi = idxs[t * 16];
#pragma unroll
        for (int j = 1; j < 16; ++j) {
            float v = vals[t * 16 + j];
            int id = idxs[t * 16 + j];
            if (v > bv || (v == bv && id < bi)) { bv = v; bi = id; }
        }
        final_idx[t] = bi;
        out_idx[row0 + t] = (float)bi;   // index as float value
    }
    __syncthreads();

    // gather: quantize[row] = embed[final_idx[row]]
    {
        int lrow = t >> 2;   // 4 threads per row
        int p = t & 3;
        int code = final_idx[lrow];
        const float4* eg = (const float4*)(embed + (size_t)code * DIM);
        float4* og = (float4*)(out_q + (size_t)(row0 + lrow) * DIM);
#pragma unroll
        for (int q = 0; q < 8; ++q) {
            int v = p + 4 * q;
            og[v] = eg[v];
        }
    }
}

extern "C" void kernel_launch(void* const* d_in, const int* in_sizes, int n_in,
                              void* d_out, int out_size, void* d_ws, size_t ws_size,
                              hipStream_t stream) {
    const float* x = (const float*)d_in[0];
    const float* embed = (const float*)d_in[1];
    float* out_q = (float*)d_out;                       // [131072*128]
    float* out_idx = out_q + (size_t)N_ROWS * DIM;      // [131072]
    float* esq = (float*)d_ws;                          // [1024]

    esq_kernel<<<BINS / 256, 256, 0, stream>>>(embed, esq);
    vq_kernel<<<N_ROWS / TM, 256, 0, stream>>>(x, embed, esq, out_q, out_idx);
}

// Round 2
// 656.416 us; speedup vs baseline: 1.1306x; 1.1306x over previous
//
#include <hip/hip_runtime.h>

// Problem: EncodecEuclideanCodebook
//   x:     [64, 2048, 128] fp32  -> N_ROWS = 131072 rows of DIM=128
//   embed: [1024, 128] fp32      -> BINS = 1024 codes
// Outputs (concatenated in d_out, read back as float32):
//   quantize [131072*128], then embed_ind [131072] (index values as floats)
//
// argmax_e ( -(||x||^2 - 2 x.e + ||e||^2) ) == argmax_e ( 2 x.e - ||e||^2 )
//
// R2: XOR-swizzled LDS layout (c' = c ^ ((r>>2)&7), LDA=128) replaces the +4
// pad. R1 had SQ_LDS_BANK_CONFLICT=2.03e8: with LDA=132 the B-fragment reads
// (row stride 4*132=528 dwords ≡ 16 mod 32) hit only 2 of 8 bank-groups.
// Swizzle spreads the 16 unique B addresses across all 8 groups (2/bank = free)
// while keeping 16B-aligned ds_read_b128 and one XOR per operand per k-step
// (a thread's 4 rows share r>>2, hence share the swizzled column).

#define N_ROWS (64 * 2048)
#define DIM 128
#define BINS 1024
#define TM 64          // rows per block
#define TN 64          // bins per chunk
#define LDA 128        // no pad; swizzle handles banks

// float4-group column swizzle: r = row, c = k/4 (0..31)
#define SWZ(r, c) (((r) * LDA) + 4 * ((c) ^ (((r) >> 2) & 7)))

__global__ __launch_bounds__(256) void esq_kernel(const float* __restrict__ embed,
                                                  float* __restrict__ esq) {
    int bin = blockIdx.x * 256 + threadIdx.x;
    if (bin >= BINS) return;
    const float4* e4 = (const float4*)(embed + (size_t)bin * DIM);
    float s = 0.f;
#pragma unroll
    for (int q = 0; q < DIM / 4; ++q) {
        float4 v = e4[q];
        s += v.x * v.x + v.y * v.y + v.z * v.z + v.w * v.w;
    }
    esq[bin] = s;
}

__global__ __launch_bounds__(256, 2) void vq_kernel(const float* __restrict__ x,
                                                    const float* __restrict__ embed,
                                                    const float* __restrict__ esq,
                                                    float* __restrict__ out_q,
                                                    float* __restrict__ out_idx) {
    __shared__ float As[TM * LDA];      // x tile: 64 rows x 128, swizzled
    __shared__ float Bs[TN * LDA];      // embed chunk: 64 bins x 128, swizzled
    __shared__ float esq_s[BINS];
    __shared__ int final_idx[TM];

    const int t = threadIdx.x;
    const int row0 = blockIdx.x * TM;

    // stage e_sq (1024 floats)
#pragma unroll
    for (int i = 0; i < BINS / 256; ++i) esq_s[t + 256 * i] = esq[t + 256 * i];

    // stage A tile: 64x128 fp32 = 2048 float4, 8 per thread, coalesced reads
    {
        const float4* xg = (const float4*)(x + (size_t)row0 * DIM);
#pragma unroll
        for (int q = 0; q < 8; ++q) {
            int f = q * 256 + t;
            int r = f >> 5;   // 32 float4 per row
            int c = f & 31;
            float4 v = xg[f];
            *(float4*)&As[SWZ(r, c)] = v;
        }
    }

    const int tx = t & 15;   // bin group within chunk (4 bins each)
    const int ty = t >> 4;   // row group (4 rows each)
    const int swzA = ty & 7; // (4*ty+i)>>2 == ty for i<4
    const int swzB = tx & 7; // (4*tx+j)>>2 == tx for j<4

    float best[4];
    int bidx[4];
#pragma unroll
    for (int i = 0; i < 4; ++i) { best[i] = -3.4e38f; bidx[i] = 0; }

    for (int chunk = 0; chunk < BINS / TN; ++chunk) {
        __syncthreads();  // protect As (chunk 0) / Bs reuse (chunk > 0)
        // stage B chunk: 64 bins x 128
        {
            const float4* eg = (const float4*)(embed + (size_t)chunk * TN * DIM);
#pragma unroll
            for (int q = 0; q < 8; ++q) {
                int f = q * 256 + t;
                int r = f >> 5;
                int c = f & 31;
                float4 v = eg[f];
                *(float4*)&Bs[SWZ(r, c)] = v;
            }
        }
        __syncthreads();

        float acc[4][4];
#pragma unroll
        for (int i = 0; i < 4; ++i)
#pragma unroll
            for (int j = 0; j < 4; ++j) acc[i][j] = 0.f;

#pragma unroll 8
        for (int c = 0; c < DIM / 4; ++c) {
            float4 a[4], b[4];
            const int ca = 4 * (c ^ swzA);
            const int cb = 4 * (c ^ swzB);
#pragma unroll
            for (int i = 0; i < 4; ++i) a[i] = *(const float4*)&As[(4 * ty + i) * LDA + ca];
#pragma unroll
            for (int j = 0; j < 4; ++j) b[j] = *(const float4*)&Bs[(4 * tx + j) * LDA + cb];
#pragma unroll
            for (int i = 0; i < 4; ++i)
#pragma unroll
                for (int j = 0; j < 4; ++j) {
                    acc[i][j] = fmaf(a[i].x, b[j].x, acc[i][j]);
                    acc[i][j] = fmaf(a[i].y, b[j].y, acc[i][j]);
                    acc[i][j] = fmaf(a[i].z, b[j].z, acc[i][j]);
                    acc[i][j] = fmaf(a[i].w, b[j].w, acc[i][j]);
                }
        }

        const int binbase = chunk * TN + 4 * tx;
#pragma unroll
        for (int i = 0; i < 4; ++i)
#pragma unroll
            for (int j = 0; j < 4; ++j) {
                float sc = 2.f * acc[i][j] - esq_s[binbase + j];
                // bins scanned in increasing order within this thread:
                // strict > keeps first (lowest) index on exact ties
                if (sc > best[i]) { best[i] = sc; bidx[i] = binbase + j; }
            }
    }

    // cross-thread (tx) argmax reduce per row; reuse As/Bs as scratch
    __syncthreads();
    float* vals = As;           // [64][16]
    int* idxs = (int*)Bs;       // [64][16]
#pragma unroll
    for (int i = 0; i < 4; ++i) {
        int r = 4 * ty + i;
        vals[r * 16 + tx] = best[i];
        idxs[r * 16 + tx] = bidx[i];
    }
    __syncthreads();
    if (t < TM) {
        float bv = vals[t * 16];
        int bi = idxs[t * 16];
#pragma unroll
        for (int j = 1; j < 16; ++j) {
            float v = vals[t * 16 + j];
            int id = idxs[t * 16 + j];
            if (v > bv || (v == bv && id < bi)) { bv = v; bi = id; }
        }
        final_idx[t] = bi;
        out_idx[row0 + t] = (float)bi;   // index as float value
    }
    __syncthreads();

    // gather: quantize[row] = embed[final_idx[row]]
    {
        int lrow = t >> 2;   // 4 threads per row
        int p = t & 3;
        int code = final_idx[lrow];
        const float4* eg = (const float4*)(embed + (size_t)code * DIM);
        float4* og = (float4*)(out_q + (size_t)(row0 + lrow) * DIM);
#pragma unroll
        for (int q = 0; q < 8; ++q) {
            int v = p + 4 * q;
            og[v] = eg[v];
        }
    }
}

extern "C" void kernel_launch(void* const* d_in, const int* in_sizes, int n_in,
                              void* d_out, int out_size, void* d_ws, size_t ws_size,
                              hipStream_t stream) {
    const float* x = (const float*)d_in[0];
    const float* embed = (const float*)d_in[1];
    float* out_q = (float*)d_out;                       // [131072*128]
    float* out_idx = out_q + (size_t)N_ROWS * DIM;      // [131072]
    float* esq = (float*)d_ws;                          // [1024]

    esq_kernel<<<BINS / 256, 256, 0, stream>>>(embed, esq);
    vq_kernel<<<N_ROWS / TM, 256, 0, stream>>>(x, embed, esq, out_q, out_idx);
}

// Round 3
// 374.878 us; speedup vs baseline: 1.9796x; 1.7510x over previous
//
#include <hip/hip_runtime.h>

// EncodecEuclideanCodebook — R3: split-bf16 MFMA scoring + margin-guarded exact refine.
//   x: [131072, 128] fp32, embed: [1024, 128] fp32.
//   out: quantize [131072*128] f32, then embed_ind [131072] (index values as f32).
//
// score(row,bin) = 2*x.e - ||e||^2 (argmax-equivalent to reference).
// x.e approximated by K=384 bf16 GEMM: x_hi.e_hi + x_lo.e_hi + x_hi.e_lo
// (error <= ~6e-3). Rows with top1-top2 gap < MARGIN=0.05 are re-scored exactly
// in fp32 (identical arithmetic to the R2 kernel that matched reference absmax 0).

#define N_ROWS (64 * 2048)
#define DIM 128
#define BINS 1024
#define MARGIN 0.05f

typedef __attribute__((ext_vector_type(8))) short short8;  // 8 bf16 = 4 VGPR
typedef __attribute__((ext_vector_type(4))) float f32x4;   // MFMA 16x16x32 acc

__device__ __forceinline__ unsigned short f2bf(float f) {   // RNE fp32->bf16
    unsigned u = __float_as_uint(f);
    u += 0x7fffu + ((u >> 16) & 1u);
    return (unsigned short)(u >> 16);
}
__device__ __forceinline__ float bf2f(unsigned short h) {
    return __uint_as_float(((unsigned)h) << 16);
}
__device__ __forceinline__ void glds16(const void* g, void* l) {
    __builtin_amdgcn_global_load_lds((const __attribute__((address_space(1))) char*)g,
                                     (__attribute__((address_space(3))) char*)l, 16, 0, 0);
}

// ws images: 32 stages x 16 KB. Stage S = chunk*8 + is_lo*4 + ks holds
// bins [256*chunk, +256) x k [32*ks, +32) of e_hi/e_lo, laid out exactly as the
// LDS ebuf: byte off = b*64 + 16*(g2 ^ ((b>>2)&3))  (b = bin&255, g2 = k-group 0..3).
__global__ __launch_bounds__(256) void prep_kernel(const float* __restrict__ embed,
                                                   short* __restrict__ e_img,
                                                   float* __restrict__ esq_g) {
    int bin = blockIdx.x * 256 + threadIdx.x;
    const float4* e4 = (const float4*)(embed + (size_t)bin * DIM);
    int c = bin >> 8, b = bin & 255;
    float s = 0.f;
#pragma unroll
    for (int g = 0; g < 16; ++g) {
        float4 v0 = e4[2 * g], v1 = e4[2 * g + 1];
        s += v0.x * v0.x + v0.y * v0.y + v0.z * v0.z + v0.w * v0.w;
        s += v1.x * v1.x + v1.y * v1.y + v1.z * v1.z + v1.w * v1.w;
        float f[8] = {v0.x, v0.y, v0.z, v0.w, v1.x, v1.y, v1.z, v1.w};
        short8 H, L;
#pragma unroll
        for (int j = 0; j < 8; ++j) {
            unsigned short h = f2bf(f[j]);
            H[j] = (short)h;
            L[j] = (short)f2bf(f[j] - bf2f(h));
        }
        int ks = g >> 2, g2 = g & 3;
        size_t off = ((size_t)(c * 8 + ks) << 14) + (size_t)b * 64 + 16 * (g2 ^ ((b >> 2) & 3));
        *(short8*)((char*)e_img + off) = H;
        *(short8*)((char*)e_img + off + (size_t)(4 << 14)) = L;   // lo stages at +4
    }
    esq_g[bin] = s;
}

__global__ __launch_bounds__(256, 3) void vq_mfma_kernel(const float* __restrict__ x,
                                                         const short* __restrict__ e_img,
                                                         const float* __restrict__ esq_g,
                                                         float* __restrict__ out_idx,
                                                         unsigned char* __restrict__ flags) {
    __shared__ __align__(16) short xh_s[64 * 128];   // 16 KB, swizzled [row][kgroup^row&7]
    __shared__ __align__(16) short xl_s[64 * 128];   // 16 KB
    __shared__ __align__(16) short eb_s[8192];       // 16 KB stage buffer

    const int t = threadIdx.x;
    const int wv = t >> 6, lane = t & 63, q = lane >> 4, L15 = lane & 15;
    const int R0 = blockIdx.x * 64;

    // ---- stage x tile -> bf16 hi/lo, swizzled (16B group g stored at g^(row&7)) ----
    {
        const float4* xg = (const float4*)(x + (size_t)R0 * DIM);
#pragma unroll
        for (int qq = 0; qq < 4; ++qq) {
            int G = qq * 256 + t;
            int row = G >> 4, g = G & 15;
            float4 v0 = xg[row * 32 + 2 * g];
            float4 v1 = xg[row * 32 + 2 * g + 1];
            float f[8] = {v0.x, v0.y, v0.z, v0.w, v1.x, v1.y, v1.z, v1.w};
            short8 H, L;
#pragma unroll
            for (int j = 0; j < 8; ++j) {
                unsigned short h = f2bf(f[j]);
                H[j] = (short)h;
                L[j] = (short)f2bf(f[j] - bf2f(h));
            }
            int off = row * 256 + 16 * (g ^ (row & 7));
            *(short8*)((char*)xh_s + off) = H;
            *(short8*)((char*)xl_s + off) = L;
        }
    }

    float best[4], sec[4];
    int bidx[4];
#pragma unroll
    for (int nt = 0; nt < 4; ++nt) { best[nt] = -3.4e38f; sec[nt] = -3.4e38f; bidx[nt] = 0; }

    const int sA = 16 * (q ^ ((L15 >> 2) & 3));      // ebuf slot swizzle (uniform in mt)
    const int aBase = (64 * wv + L15) * 64 + sA;

    for (int c = 0; c < 4; ++c) {                    // 4 chunks of 256 bins
        f32x4 acc[4][4];
#pragma unroll
        for (int mt = 0; mt < 4; ++mt)
#pragma unroll
            for (int nt = 0; nt < 4; ++nt) acc[mt][nt] = (f32x4){0.f, 0.f, 0.f, 0.f};

        for (int s = 0; s < 8; ++s) {                // 4 e_hi k-stages, then 4 e_lo
            __syncthreads();                          // readers of prev stage done
            const char* src = (const char*)e_img + ((size_t)(c * 8 + s) << 14);
#pragma unroll
            for (int i = 0; i < 4; ++i) {
                int off = ((i << 2) | wv) << 10;     // wave-uniform 1KB segments
                glds16(src + off + lane * 16, (char*)eb_s + off);
            }
            __syncthreads();                          // glds landed

            const int ks = s & 3;
            const int sB = 16 * ((((ks << 2) | q)) ^ (lane & 7));
            short8 a[4];
#pragma unroll
            for (int mt = 0; mt < 4; ++mt)
                a[mt] = *(const short8*)((const char*)eb_s + aBase + mt * 1024);
            short8 bfr[4];
#pragma unroll
            for (int nt = 0; nt < 4; ++nt)
                bfr[nt] = *(const short8*)((const char*)xh_s + (16 * nt + L15) * 256 + sB);
#pragma unroll
            for (int mt = 0; mt < 4; ++mt)
#pragma unroll
                for (int nt = 0; nt < 4; ++nt)
                    acc[mt][nt] = __builtin_amdgcn_mfma_f32_16x16x32_bf16(a[mt], bfr[nt], acc[mt][nt], 0, 0, 0);
            if (s < 4) {                              // e_hi also pairs with x_lo
#pragma unroll
                for (int nt = 0; nt < 4; ++nt)
                    bfr[nt] = *(const short8*)((const char*)xl_s + (16 * nt + L15) * 256 + sB);
#pragma unroll
                for (int mt = 0; mt < 4; ++mt)
#pragma unroll
                    for (int nt = 0; nt < 4; ++nt)
                        acc[mt][nt] = __builtin_amdgcn_mfma_f32_16x16x32_bf16(a[mt], bfr[nt], acc[mt][nt], 0, 0, 0);
            }
        }

        // ---- chunk epilogue: score + per-lane top-2 (bins ascending per lane) ----
        float es[4][4];
        const float* ep = esq_g + 256 * c + 64 * wv + 4 * q;
#pragma unroll
        for (int mt = 0; mt < 4; ++mt)
#pragma unroll
            for (int r = 0; r < 4; ++r) es[mt][r] = ep[16 * mt + r];
#pragma unroll
        for (int mt = 0; mt < 4; ++mt)
#pragma unroll
            for (int r = 0; r < 4; ++r) {
                int bin = 256 * c + 64 * wv + 16 * mt + 4 * q + r;
                float e2 = es[mt][r];
#pragma unroll
                for (int nt = 0; nt < 4; ++nt) {
                    float sc = 2.f * acc[mt][nt][r] - e2;
                    if (sc > best[nt]) { sec[nt] = best[nt]; best[nt] = sc; bidx[nt] = bin; }
                    else if (sc > sec[nt]) sec[nt] = sc;
                }
            }
    }

    // ---- cross-quad top-2 merge (exact ties collapse gap to 0 -> flagged) ----
#pragma unroll
    for (int nt = 0; nt < 4; ++nt) {
        for (int off = 16; off <= 32; off <<= 1) {
            float ob = __shfl_xor(best[nt], off);
            float os = __shfl_xor(sec[nt], off);
            int oi = __shfl_xor(bidx[nt], off);
            if (ob > best[nt]) { sec[nt] = fmaxf(best[nt], os); best[nt] = ob; bidx[nt] = oi; }
            else sec[nt] = fmaxf(sec[nt], ob);
        }
    }
    __syncthreads();                                  // safe to reuse eb_s
    float* sv = (float*)eb_s;                         // [wave][64 rows][best,sec,idx]
    if (q == 0) {
#pragma unroll
        for (int nt = 0; nt < 4; ++nt) {
            int base = (wv * 64 + 16 * nt + L15) * 3;
            sv[base] = best[nt]; sv[base + 1] = sec[nt];
            ((int*)sv)[base + 2] = bidx[nt];
        }
    }
    __syncthreads();
    if (t < 64) {
        float b0 = sv[t * 3], s0 = sv[t * 3 + 1];
        int i0 = ((int*)sv)[t * 3 + 2];
        for (int w = 1; w < 4; ++w) {
            int base = (w * 64 + t) * 3;
            float ob = sv[base], os = sv[base + 1];
            int oi = ((int*)sv)[base + 2];
            if (ob > b0) { s0 = fmaxf(b0, os); b0 = ob; i0 = oi; }
            else s0 = fmaxf(s0, ob);
        }
        out_idx[R0 + t] = (float)i0;
        flags[R0 + t] = (b0 - s0 < MARGIN) ? 1 : 0;
    }
}

// Exact fp32 re-score of flagged rows — arithmetic identical to the R2 kernel
// (proven absmax 0 vs reference): per-bin dot via float4 fmaf chain, first-max tie-break.
__global__ __launch_bounds__(256) void refine_kernel(const float* __restrict__ x,
                                                     const float* __restrict__ embed,
                                                     const float* __restrict__ esq_g,
                                                     float* __restrict__ out_idx,
                                                     const unsigned char* __restrict__ flags) {
    __shared__ float4 xr[32];
    __shared__ float rv[256];
    __shared__ int ri[256];
    __shared__ unsigned char fl[256];
    int t = threadIdx.x;
    int r0 = blockIdx.x * 256;
    fl[t] = flags[r0 + t];
    __syncthreads();
    for (int i = 0; i < 256; ++i) {
        if (!fl[i]) continue;                         // uniform branch
        int row = r0 + i;
        if (t < 32) xr[t] = ((const float4*)(x + (size_t)row * DIM))[t];
        __syncthreads();
        float bb = -3.4e38f; int bbi = 0;
        for (int u = 0; u < 4; ++u) {
            int bin = u * 256 + t;
            const float4* e4 = (const float4*)(embed + (size_t)bin * DIM);
            float acc = 0.f;
#pragma unroll 8
            for (int c2 = 0; c2 < 32; ++c2) {
                float4 a = xr[c2]; float4 b = e4[c2];
                acc = fmaf(a.x, b.x, acc); acc = fmaf(a.y, b.y, acc);
                acc = fmaf(a.z, b.z, acc); acc = fmaf(a.w, b.w, acc);
            }
            float sc = 2.f * acc - esq_g[bin];
            if (sc > bb) { bb = sc; bbi = bin; }      // bins ascending in u
        }
        rv[t] = bb; ri[t] = bbi;
        __syncthreads();
        for (int sft = 128; sft > 0; sft >>= 1) {
            if (t < sft) {
                float v = rv[t + sft]; int id = ri[t + sft];
                if (v > rv[t] || (v == rv[t] && id < ri[t])) { rv[t] = v; ri[t] = id; }
            }
            __syncthreads();
        }
        if (t == 0) out_idx[row] = (float)ri[0];
        __syncthreads();
    }
}

__global__ __launch_bounds__(256) void gather_kernel(const float* __restrict__ embed,
                                                     const float* __restrict__ out_idx,
                                                     float4* __restrict__ out_q4) {
    int gid = blockIdx.x * 256 + threadIdx.x;
    int row = gid >> 5, seg = gid & 31;
    int idx = (int)out_idx[row];
    out_q4[(size_t)row * 32 + seg] = ((const float4*)embed)[(size_t)idx * 32 + seg];
}

extern "C" void kernel_launch(void* const* d_in, const int* in_sizes, int n_in,
                              void* d_out, int out_size, void* d_ws, size_t ws_size,
                              hipStream_t stream) {
    const float* x = (const float*)d_in[0];
    const float* embed = (const float*)d_in[1];
    float* out_q = (float*)d_out;
    float* out_idx = out_q + (size_t)N_ROWS * DIM;
    char* wsb = (char*)d_ws;
    short* e_img = (short*)wsb;                                   // 512 KB
    float* esq_g = (float*)(wsb + (32 << 14));                    // 4 KB
    unsigned char* flags = (unsigned char*)(wsb + (32 << 14) + 4096);  // 128 KB

    prep_kernel<<<BINS / 256, 256, 0, stream>>>(embed, e_img, esq_g);
    vq_mfma_kernel<<<N_ROWS / 64, 256, 0, stream>>>(x, e_img, esq_g, out_idx, flags);
    refine_kernel<<<N_ROWS / 256, 256, 0, stream>>>(x, embed, esq_g, out_idx, flags);
    gather_kernel<<<(N_ROWS * 32) / 256, 256, 0, stream>>>(embed, out_idx, (float4*)out_q);
}